// Round 16
// baseline (237.592 us; speedup 1.0000x reference)
//
#include <hip/hip_runtime.h>
#include <hip/hip_bf16.h>
#include <math.h>

// Problem constants
#define BDEF 64
#define LSEQ 256
#define HD   4
#define NST  4
#define NBLK 2
#define SPLIT 4   // conv m-split factor in s4front

typedef float nfloat4 __attribute__((ext_vector_type(4)));  // native vec for nt ops

__device__ inline void nt_store4(const float4 v, float* p) {
    nfloat4 nv = {v.x, v.y, v.z, v.w};
    __builtin_nontemporal_store(nv, (nfloat4*)p);
}

// acc_row += a.{x,y,z,w} * w{0,1,2,3} (component-wise over 4 j)
#define ACCROW(accv, av)                                        \
    accv.x += av.x*w0.x + av.y*w1.x + av.z*w2.x + av.w*w3.x;    \
    accv.y += av.x*w0.y + av.y*w1.y + av.z*w2.y + av.w*w3.y;    \
    accv.z += av.x*w0.z + av.y*w1.z + av.z*w2.z + av.w*w3.z;    \
    accv.w += av.x*w0.w + av.y*w1.w + av.z*w2.w + av.w*w3.w;

// ---------------------------------------------------------------------------
// Kernel 1: K-comp + encoder + 2x S4D block + decoder + pooling
//           -> combined [64,1856].
// grid=64 (one block per batch), block=1024 (4 m-split parts x 256 l).
// ---------------------------------------------------------------------------
__global__ __launch_bounds__(1024) void s4front(
    const float* __restrict__ x, const float* __restrict__ enc_W,
    const float* __restrict__ enc_b, const float* __restrict__ ln_s,
    const float* __restrict__ ln_b, const float* __restrict__ log_dt,
    const float* __restrict__ A_re, const float* __restrict__ A_im,
    const float* __restrict__ C_re, const float* __restrict__ C_im,
    const float* __restrict__ Dp, const float* __restrict__ out_W,
    const float* __restrict__ out_b, const float* __restrict__ dec_W,
    const float* __restrict__ dec_b, float* __restrict__ combined)
{
    const int b    = blockIdx.x;
    const int t    = threadIdx.x;
    const int l    = t & 255;
    const int part = t >> 8;            // 0..3, wave-uniform
    __shared__ float Kl[NBLK][LSEQ][4];     // conv kernels, 8 KB
    __shared__ float x_lds[4][256];         // raw input row, 4 KB
    __shared__ float z_lds[256][4];         // pre-conv activations, 4 KB
    __shared__ float s4_lds[256][4];        // decoder output, 4 KB
    __shared__ float yp[SPLIT][256][4];     // conv partials, 16 KB

    // ---- SSM kernels K[i][m][h]: threads t<512, i=part, m=l ----
    if (t < 512) {
        const int i = part;             // 0 or 1
        const float tt = (float)l;
        #pragma unroll
        for (int h = 0; h < HD; ++h) {
            float dt = expf(log_dt[i*HD + h]);
            float acc = 0.f;
            #pragma unroll
            for (int n = 0; n < NST; ++n) {
                const int idx = (i*HD + h)*NST + n;
                float ar = -expf(A_re[idx]);     // Re(A)
                float ai = A_im[idx];            // Im(A)
                float dr = ar*dt, di = ai*dt;    // dtA
                float er  = expf(dr);            // Bd = (exp(dtA)-1)/A
                float e1r = er*cosf(di) - 1.0f;
                float e1i = er*sinf(di);
                float inv = 1.0f/(ar*ar + ai*ai);
                float bdr = (e1r*ar + e1i*ai)*inv;
                float bdi = (e1i*ar - e1r*ai)*inv;
                float cr = C_re[idx], ci = C_im[idx];
                float cbr = cr*bdr - ci*bdi;     // C*Bd
                float cbi = cr*bdi + ci*bdr;
                float em = expf(dr*tt);          // vand = exp(dtA*t)
                float vr = em*cosf(di*tt);
                float vi = em*sinf(di*tt);
                acc += cbr*vr - cbi*vi;
            }
            Kl[i][l][h] = 2.0f*acc;
        }
    }

    if (part == 0) {
        #pragma unroll
        for (int c = 0; c < 4; ++c)
            x_lds[c][l] = x[(b*4 + c)*256 + l];
    }
    __syncthreads();

    // encoder (all parts duplicate; register-only state)
    float u[4];
    #pragma unroll
    for (int h = 0; h < 4; ++h) {
        float a = enc_b[h];
        #pragma unroll
        for (int c = 0; c < 4; ++c) a += x_lds[c][l]*enc_W[c*4 + h];
        u[h] = a;
    }

    const int mlim = l | 63;            // wave-uniform conv bound
    const int m0   = part*64;           // wave-uniform part range start

    for (int i = 0; i < NBLK; ++i) {
        // prenorm LN over H=4 (all parts duplicate)
        float mu = 0.25f*(u[0]+u[1]+u[2]+u[3]);
        float var = 0.f;
        #pragma unroll
        for (int h = 0; h < 4; ++h) { float d = u[h]-mu; var += d*d; }
        var *= 0.25f;
        float rs = rsqrtf(var + 1e-5f);
        float z[4];
        #pragma unroll
        for (int h = 0; h < 4; ++h)
            z[h] = (u[h]-mu)*rs*ln_s[i*4 + h] + ln_b[i*4 + h];
        if (part == 0)
            *(float4*)&z_lds[l][0] = make_float4(z[0], z[1], z[2], z[3]);
        __syncthreads();   // A: z_lds visible to all parts

        // conv partial: m in [m0, min(m0+63, mlim)], mask m<=l
        float y0 = 0.f, y1 = 0.f, y2 = 0.f, y3 = 0.f;
        const int mhi = min(m0 + 63, mlim);
        #pragma unroll 4
        for (int m = m0; m <= mhi; ++m) {
            float4 kk = *(const float4*)&Kl[i][m][0];
            int p = (l - m) & 255;
            float4 zz = *(const float4*)&z_lds[p][0];
            if (m <= l) {
                y0 += kk.x*zz.x; y1 += kk.y*zz.y;
                y2 += kk.z*zz.z; y3 += kk.w*zz.w;
            }
        }
        *(float4*)&yp[part][l][0] = make_float4(y0, y1, y2, y3);
        __syncthreads();   // B: partials ready

        float4 p0 = *(const float4*)&yp[0][l][0];
        float4 p1 = *(const float4*)&yp[1][l][0];
        float4 p2 = *(const float4*)&yp[2][l][0];
        float4 p3 = *(const float4*)&yp[3][l][0];
        float y[4] = { p0.x+p1.x+p2.x+p3.x, p0.y+p1.y+p2.y+p3.y,
                       p0.z+p1.z+p2.z+p3.z, p0.w+p1.w+p2.w+p3.w };
        // skip + gelu (tanh approximation) — all parts duplicate
        #pragma unroll
        for (int h = 0; h < 4; ++h) {
            float v = y[h] + Dp[i*4 + h]*z[h];
            float inner = 0.7978845608028654f*(v + 0.044715f*v*v*v);
            y[h] = 0.5f*v*(1.0f + tanhf(inner));
        }
        // output projection + residual
        #pragma unroll
        for (int k = 0; k < 4; ++k) {
            float a = out_b[i*4 + k];
            #pragma unroll
            for (int h = 0; h < 4; ++h) a += y[h]*out_W[(i*4 + h)*4 + k];
            u[k] += a;
        }
        __syncthreads();   // C: yp/z_lds reads done before next-iter rewrite
    }

    // decoder (part 0 writes; all parts hold identical u)
    if (part == 0) {
        #pragma unroll
        for (int h = 0; h < 4; ++h) {
            float a = dec_b[h];
            #pragma unroll
            for (int k = 0; k < 4; ++k) a += u[k]*dec_W[k*4 + h];
            s4_lds[l][h] = a;
        }
    }
    __syncthreads();

    float* cmb = combined + b*1856;
    // z16: [4,16] pooled (window 16), flattened h*16+k
    if (t < 64) {
        int h = t >> 4, kk = t & 15;
        float a = 0.f;
        #pragma unroll
        for (int j = 0; j < 16; ++j) a += s4_lds[kk*16 + j][h];
        cmb[t] = a*(1.0f/16.0f);
    }
    // fpp: [4,448] = concat(pool64(win4), pool128(win2), raw256), offset 64
    for (int e = t; e < 1792; e += 1024) {
        int c = e/448, jj = e%448;
        float v;
        if (jj < 64) {
            v = 0.25f*(x_lds[c][4*jj] + x_lds[c][4*jj+1] +
                       x_lds[c][4*jj+2] + x_lds[c][4*jj+3]);
        } else if (jj < 192) {
            int q = jj - 64;
            v = 0.5f*(x_lds[c][2*q] + x_lds[c][2*q+1]);
        } else {
            v = x_lds[c][jj - 192];
        }
        cmb[64 + e] = v;
    }
}

// ---------------------------------------------------------------------------
// Kernel 2/4: partial GEMM, M=64 fixed, k4-vectorized ACCROW inner loop.
// Block = [KCH k-chunk] x [64 j-tile]; parts[ks][64][NCOLS].
// grid = (K/KCH, NCOLS/64), block 256. KCH=64 -> 33 KB LDS, 4 blocks/CU.
// ---------------------------------------------------------------------------
template<int NCOLS, int ASTRIDE, int KCH>
__global__ __launch_bounds__(256) void mlp_part(
    const float* __restrict__ A, const float* __restrict__ W,
    float* __restrict__ parts)
{
    constexpr int APAD = KCH + 4;
    __shared__ float At[64][APAD];     // A chunk, [b][k], padded
    __shared__ float Wl[KCH][64];      // W tile [k][j]
    const int ks = blockIdx.x, k0 = ks*KCH;
    const int j0 = blockIdx.y*64;
    const int t  = threadIdx.x;

    {
        constexpr int AF4 = 64*KCH/4;
        constexpr int RF4 = KCH/4;
        #pragma unroll
        for (int f = t; f < AF4; f += 256) {
            const int row = f / RF4, c4 = f % RF4;
            *(float4*)&At[row][c4*4] =
                *(const float4*)(A + (size_t)row*ASTRIDE + k0 + c4*4);
        }
        constexpr int WF4 = KCH*16;
        #pragma unroll
        for (int f = t; f < WF4; f += 256) {
            const int row = f >> 4, c4 = f & 15;
            *(float4*)&Wl[row][c4*4] =
                *(const float4*)(W + (size_t)(k0 + row)*NCOLS + j0 + c4*4);
        }
    }
    __syncthreads();

    const int ji = t & 15, br = (t >> 4)*4;
    float4 acc0={0,0,0,0}, acc1={0,0,0,0}, acc2={0,0,0,0}, acc3={0,0,0,0};
    #pragma unroll 4
    for (int k4 = 0; k4 < KCH; k4 += 4) {
        float4 w0 = *(float4*)&Wl[k4+0][ji*4];
        float4 w1 = *(float4*)&Wl[k4+1][ji*4];
        float4 w2 = *(float4*)&Wl[k4+2][ji*4];
        float4 w3 = *(float4*)&Wl[k4+3][ji*4];
        float4 a0 = *(float4*)&At[br+0][k4];
        float4 a1 = *(float4*)&At[br+1][k4];
        float4 a2 = *(float4*)&At[br+2][k4];
        float4 a3 = *(float4*)&At[br+3][k4];
        ACCROW(acc0, a0) ACCROW(acc1, a1) ACCROW(acc2, a2) ACCROW(acc3, a3)
    }
    float* pbase = parts + (size_t)(ks*64 + br)*NCOLS + j0 + ji*4;
    *(float4*)(pbase)           = acc0;
    *(float4*)(pbase + NCOLS)   = acc1;
    *(float4*)(pbase + 2*NCOLS) = acc2;
    *(float4*)(pbase + 3*NCOLS) = acc3;
}

// ---------------------------------------------------------------------------
// Kernel 3/5: sum partials + bias, then LayerNorm + ReLU.  grid=64 (per b).
// ---------------------------------------------------------------------------
template<int N>
__global__ __launch_bounds__(256) void reduce_ln_relu(
    const float* __restrict__ parts, const float* __restrict__ bias,
    const float* __restrict__ g, const float* __restrict__ be,
    float* __restrict__ out, int KS)
{
    constexpr int NV = N/1024;      // float4 per thread
    const int b = blockIdx.x, t = threadIdx.x;
    float4 acc[NV];
    #pragma unroll
    for (int v = 0; v < NV; ++v)
        acc[v] = *(const float4*)(bias + v*1024 + t*4);
    for (int ks = 0; ks < KS; ++ks) {
        const float* p = parts + (size_t)(ks*64 + b)*N;
        #pragma unroll
        for (int v = 0; v < NV; ++v) {
            float4 q = *(const float4*)(p + v*1024 + t*4);
            acc[v].x += q.x; acc[v].y += q.y; acc[v].z += q.z; acc[v].w += q.w;
        }
    }
    float s = 0.f, s2 = 0.f;
    #pragma unroll
    for (int v = 0; v < NV; ++v) {
        s  += acc[v].x + acc[v].y + acc[v].z + acc[v].w;
        s2 += acc[v].x*acc[v].x + acc[v].y*acc[v].y +
              acc[v].z*acc[v].z + acc[v].w*acc[v].w;
    }
    #pragma unroll
    for (int off = 32; off > 0; off >>= 1) {
        s  += __shfl_down(s,  off);
        s2 += __shfl_down(s2, off);
    }
    __shared__ float red[2][4];
    const int w = t >> 6;
    if ((t & 63) == 0) { red[0][w] = s; red[1][w] = s2; }
    __syncthreads();
    float ts  = red[0][0] + red[0][1] + red[0][2] + red[0][3];
    float ts2 = red[1][0] + red[1][1] + red[1][2] + red[1][3];
    const float inv_n = 1.0f/(float)N;
    float mu  = ts*inv_n;
    float var = ts2*inv_n - mu*mu;
    float rs  = rsqrtf(var + 1e-5f);
    #pragma unroll
    for (int v = 0; v < NV; ++v) {
        const int j = v*1024 + t*4;
        float4 gv  = *(const float4*)(g + j);
        float4 bev = *(const float4*)(be + j);
        float4 o;
        o.x = fmaxf((acc[v].x - mu)*rs*gv.x + bev.x, 0.f);
        o.y = fmaxf((acc[v].y - mu)*rs*gv.y + bev.y, 0.f);
        o.z = fmaxf((acc[v].z - mu)*rs*gv.z + bev.z, 0.f);
        o.w = fmaxf((acc[v].w - mu)*rs*gv.w + bev.w, 0.f);
        *(float4*)(out + (size_t)b*N + j) = o;
    }
}

// ---------------------------------------------------------------------------
// Kernel 6: out[b,s,:] = h2[b, s*8 .. s*8+7] @ W3 + b3 -> [64,512,4096] f32
// grid = (512 row-groups of 64 rows, 4 j-slices of 1024), block 256.
// h2 reads wave-uniform -> s_load (K$); W3 in registers; NT float4 stores.
// ---------------------------------------------------------------------------
#define ROWS_D 64
__global__ __launch_bounds__(256) void final_mm(
    const float* __restrict__ h2, const float* __restrict__ W3,
    const float* __restrict__ b3, float* __restrict__ out)
{
    const int rg = blockIdx.x;
    const int js = blockIdx.y;
    const int t  = threadIdx.x;
    const int bs0 = rg*ROWS_D;
    const int j = js*1024 + t*4;
    float4 w[8];
    #pragma unroll
    for (int k = 0; k < 8; ++k) w[k] = *(const float4*)(W3 + k*4096 + j);
    const float4 bv = *(const float4*)(b3 + j);
    const float* __restrict__ hrow = h2 + (size_t)bs0*8;
    float* __restrict__ obase = out + (size_t)bs0*4096 + j;
    #pragma unroll 4
    for (int r = 0; r < ROWS_D; ++r) {
        float4 acc = bv;
        #pragma unroll
        for (int k = 0; k < 8; ++k) {
            const float hv = hrow[r*8 + k];   // wave-uniform -> s_load (K$)
            acc.x += hv*w[k].x; acc.y += hv*w[k].y;
            acc.z += hv*w[k].z; acc.w += hv*w[k].w;
        }
        nt_store4(acc, obase + (size_t)r*4096);
    }
}

// ---------------------------------------------------------------------------
extern "C" void kernel_launch(void* const* d_in, const int* in_sizes, int n_in,
                              void* d_out, int out_size, void* d_ws, size_t ws_size,
                              hipStream_t stream) {
    const float* x      = (const float*)d_in[0];
    const float* enc_W  = (const float*)d_in[1];
    const float* enc_b  = (const float*)d_in[2];
    const float* ln_s   = (const float*)d_in[3];
    const float* ln_b   = (const float*)d_in[4];
    const float* log_dt = (const float*)d_in[5];
    const float* A_re   = (const float*)d_in[6];
    const float* A_im   = (const float*)d_in[7];
    const float* C_re   = (const float*)d_in[8];
    const float* C_im   = (const float*)d_in[9];
    const float* Dp     = (const float*)d_in[10];
    const float* out_W  = (const float*)d_in[11];
    const float* out_b  = (const float*)d_in[12];
    const float* dec_W  = (const float*)d_in[13];
    const float* dec_b  = (const float*)d_in[14];
    const float* W1     = (const float*)d_in[15];
    const float* b1     = (const float*)d_in[16];
    const float* g1     = (const float*)d_in[17];
    const float* be1    = (const float*)d_in[18];
    const float* W2     = (const float*)d_in[19];
    const float* b2     = (const float*)d_in[20];
    const float* g2     = (const float*)d_in[21];
    const float* be2    = (const float*)d_in[22];
    const float* W3     = (const float*)d_in[23];
    const float* b3     = (const float*)d_in[24];
    float* out = (float*)d_out;

    float* ws = (float*)d_ws;
    float* combined = ws;                        // 64*1856
    float* parts1   = combined + 64*1856;        // 29*64*1024
    float* h1       = parts1 + 29*64*1024;       // 64*1024
    float* parts2   = h1 + 64*1024;              // 16*64*4096
    float* h2       = parts2 + 16*64*4096;       // 64*4096

    // ---- MEASUREMENT: s4front x4 (3 extra, idempotent) ----
    // S = (dur - 166.6)/3 ; GEMM-chain = 65.6 - S.
    s4front<<<64, 1024, 0, stream>>>(x, enc_W, enc_b, ln_s, ln_b, log_dt,
                                     A_re, A_im, C_re, C_im, Dp,
                                     out_W, out_b, dec_W, dec_b, combined);
    s4front<<<64, 1024, 0, stream>>>(x, enc_W, enc_b, ln_s, ln_b, log_dt,
                                     A_re, A_im, C_re, C_im, Dp,
                                     out_W, out_b, dec_W, dec_b, combined);
    s4front<<<64, 1024, 0, stream>>>(x, enc_W, enc_b, ln_s, ln_b, log_dt,
                                     A_re, A_im, C_re, C_im, Dp,
                                     out_W, out_b, dec_W, dec_b, combined);
    s4front<<<64, 1024, 0, stream>>>(x, enc_W, enc_b, ln_s, ln_b, log_dt,
                                     A_re, A_im, C_re, C_im, Dp,
                                     out_W, out_b, dec_W, dec_b, combined);
    mlp_part<1024,1856,64><<<dim3(29,16), 256, 0, stream>>>(combined, W1, parts1);
    reduce_ln_relu<1024><<<64, 256, 0, stream>>>(parts1, b1, g1, be1, h1, 29);
    mlp_part<4096,1024,64><<<dim3(16,64), 256, 0, stream>>>(h1, W2, parts2);
    reduce_ln_relu<4096><<<64, 256, 0, stream>>>(parts2, b2, g2, be2, h2, 16);
    final_mm<<<dim3(512,4), 256, 0, stream>>>(h2, W3, b3, out);
}

// Round 17
// 172.200 us; speedup vs baseline: 1.3797x; 1.3797x over previous
//
#include <hip/hip_runtime.h>
#include <hip/hip_bf16.h>
#include <math.h>

// Problem constants
#define BDEF 64
#define LSEQ 256
#define HD   4
#define NST  4
#define NBLK 2
#define SPLIT 4   // conv m-split factor in s4front

typedef float nfloat4 __attribute__((ext_vector_type(4)));  // native vec for nt ops

__device__ inline void nt_store4(const float4 v, float* p) {
    nfloat4 nv = {v.x, v.y, v.z, v.w};
    __builtin_nontemporal_store(nv, (nfloat4*)p);
}

__device__ inline float rl(float v, int lane) {   // wave-uniform lane broadcast
    return __int_as_float(__builtin_amdgcn_readlane(__float_as_int(v), lane));
}

// acc_row += a.{x,y,z,w} * w{0,1,2,3} (component-wise over 4 j)
#define ACCROW(accv, av)                                        \
    accv.x += av.x*w0.x + av.y*w1.x + av.z*w2.x + av.w*w3.x;    \
    accv.y += av.x*w0.y + av.y*w1.y + av.z*w2.y + av.w*w3.y;    \
    accv.z += av.x*w0.z + av.y*w1.z + av.z*w2.z + av.w*w3.z;    \
    accv.w += av.x*w0.w + av.y*w1.w + av.z*w2.w + av.w*w3.w;

// ---------------------------------------------------------------------------
// Kernel 1: K-comp + encoder + 2x S4D block + decoder + pooling
//           -> combined [64,1856].
// grid=64 (one block per batch), block=1024 (4 m-split parts x 256 l).
// K enters the conv loop via v_readlane (VALU) instead of ds_read: lane j
// of each wave holds K[i][m0+j]; the per-iter broadcast leaves the LDS pipe.
// ---------------------------------------------------------------------------
__global__ __launch_bounds__(1024) void s4front(
    const float* __restrict__ x, const float* __restrict__ enc_W,
    const float* __restrict__ enc_b, const float* __restrict__ ln_s,
    const float* __restrict__ ln_b, const float* __restrict__ log_dt,
    const float* __restrict__ A_re, const float* __restrict__ A_im,
    const float* __restrict__ C_re, const float* __restrict__ C_im,
    const float* __restrict__ Dp, const float* __restrict__ out_W,
    const float* __restrict__ out_b, const float* __restrict__ dec_W,
    const float* __restrict__ dec_b, float* __restrict__ combined)
{
    const int b    = blockIdx.x;
    const int t    = threadIdx.x;
    const int l    = t & 255;
    const int part = t >> 8;            // 0..3, wave-uniform
    const int lane = t & 63;
    __shared__ float Kl[NBLK][LSEQ][4];     // conv kernels, 8 KB
    __shared__ float x_lds[4][256];         // raw input row, 4 KB
    __shared__ float z_lds[256][4];         // pre-conv activations, 4 KB
    __shared__ float s4_lds[256][4];        // decoder output, 4 KB
    __shared__ float yp[SPLIT][256][4];     // conv partials, 16 KB

    // ---- SSM kernels K[i][m][h]: threads t<512, i=part, m=l ----
    if (t < 512) {
        const int i = part;             // 0 or 1
        const float tt = (float)l;
        #pragma unroll
        for (int h = 0; h < HD; ++h) {
            float dt = expf(log_dt[i*HD + h]);
            float acc = 0.f;
            #pragma unroll
            for (int n = 0; n < NST; ++n) {
                const int idx = (i*HD + h)*NST + n;
                float ar = -expf(A_re[idx]);     // Re(A)
                float ai = A_im[idx];            // Im(A)
                float dr = ar*dt, di = ai*dt;    // dtA
                float er  = expf(dr);            // Bd = (exp(dtA)-1)/A
                float e1r = er*cosf(di) - 1.0f;
                float e1i = er*sinf(di);
                float inv = 1.0f/(ar*ar + ai*ai);
                float bdr = (e1r*ar + e1i*ai)*inv;
                float bdi = (e1i*ar - e1r*ai)*inv;
                float cr = C_re[idx], ci = C_im[idx];
                float cbr = cr*bdr - ci*bdi;     // C*Bd
                float cbi = cr*bdi + ci*bdr;
                float em = expf(dr*tt);          // vand = exp(dtA*t)
                float vr = em*cosf(di*tt);
                float vi = em*sinf(di*tt);
                acc += cbr*vr - cbi*vi;
            }
            Kl[i][l][h] = 2.0f*acc;
        }
    }

    if (part == 0) {
        #pragma unroll
        for (int c = 0; c < 4; ++c)
            x_lds[c][l] = x[(b*4 + c)*256 + l];
    }
    __syncthreads();

    // encoder (all parts duplicate; register-only state)
    float u[4];
    #pragma unroll
    for (int h = 0; h < 4; ++h) {
        float a = enc_b[h];
        #pragma unroll
        for (int c = 0; c < 4; ++c) a += x_lds[c][l]*enc_W[c*4 + h];
        u[h] = a;
    }

    const int mlim = l | 63;            // wave-uniform conv bound
    const int m0   = part*64;           // wave-uniform part range start

    for (int i = 0; i < NBLK; ++i) {
        // per-wave K preload: lane j holds K[i][m0+j][0..3] (1 LDS read/layer)
        const float4 kreg = *(const float4*)&Kl[i][m0 + lane][0];

        // prenorm LN over H=4 (all parts duplicate)
        float mu = 0.25f*(u[0]+u[1]+u[2]+u[3]);
        float var = 0.f;
        #pragma unroll
        for (int h = 0; h < 4; ++h) { float d = u[h]-mu; var += d*d; }
        var *= 0.25f;
        float rs = rsqrtf(var + 1e-5f);
        float z[4];
        #pragma unroll
        for (int h = 0; h < 4; ++h)
            z[h] = (u[h]-mu)*rs*ln_s[i*4 + h] + ln_b[i*4 + h];
        if (part == 0)
            *(float4*)&z_lds[l][0] = make_float4(z[0], z[1], z[2], z[3]);
        __syncthreads();   // A: z_lds visible to all parts

        // conv partial: m in [m0, m0+64) (wave-level skip if fully masked);
        // K broadcast via v_readlane (VALU), z gather via ds_read_b128.
        float y0 = 0.f, y1 = 0.f, y2 = 0.f, y3 = 0.f;
        if (m0 <= mlim) {
            #pragma unroll 4
            for (int idx = 0; idx < 64; ++idx) {
                const int m = m0 + idx;
                const float kx = rl(kreg.x, idx);
                const float ky = rl(kreg.y, idx);
                const float kz = rl(kreg.z, idx);
                const float kw = rl(kreg.w, idx);
                const int p = (l - m) & 255;
                const float4 zz = *(const float4*)&z_lds[p][0];
                if (m <= l) {
                    y0 += kx*zz.x; y1 += ky*zz.y;
                    y2 += kz*zz.z; y3 += kw*zz.w;
                }
            }
        }
        *(float4*)&yp[part][l][0] = make_float4(y0, y1, y2, y3);
        __syncthreads();   // B: partials ready

        float4 p0 = *(const float4*)&yp[0][l][0];
        float4 p1 = *(const float4*)&yp[1][l][0];
        float4 p2 = *(const float4*)&yp[2][l][0];
        float4 p3 = *(const float4*)&yp[3][l][0];
        float y[4] = { p0.x+p1.x+p2.x+p3.x, p0.y+p1.y+p2.y+p3.y,
                       p0.z+p1.z+p2.z+p3.z, p0.w+p1.w+p2.w+p3.w };
        // skip + gelu (tanh approximation) — all parts duplicate
        #pragma unroll
        for (int h = 0; h < 4; ++h) {
            float v = y[h] + Dp[i*4 + h]*z[h];
            float inner = 0.7978845608028654f*(v + 0.044715f*v*v*v);
            y[h] = 0.5f*v*(1.0f + tanhf(inner));
        }
        // output projection + residual
        #pragma unroll
        for (int k = 0; k < 4; ++k) {
            float a = out_b[i*4 + k];
            #pragma unroll
            for (int h = 0; h < 4; ++h) a += y[h]*out_W[(i*4 + h)*4 + k];
            u[k] += a;
        }
        __syncthreads();   // C: yp/z_lds reads done before next-iter rewrite
    }

    // decoder (part 0 writes; all parts hold identical u)
    if (part == 0) {
        #pragma unroll
        for (int h = 0; h < 4; ++h) {
            float a = dec_b[h];
            #pragma unroll
            for (int k = 0; k < 4; ++k) a += u[k]*dec_W[k*4 + h];
            s4_lds[l][h] = a;
        }
    }
    __syncthreads();

    float* cmb = combined + b*1856;
    // z16: [4,16] pooled (window 16), flattened h*16+k
    if (t < 64) {
        int h = t >> 4, kk = t & 15;
        float a = 0.f;
        #pragma unroll
        for (int j = 0; j < 16; ++j) a += s4_lds[kk*16 + j][h];
        cmb[t] = a*(1.0f/16.0f);
    }
    // fpp: [4,448] = concat(pool64(win4), pool128(win2), raw256), offset 64
    for (int e = t; e < 1792; e += 1024) {
        int c = e/448, jj = e%448;
        float v;
        if (jj < 64) {
            v = 0.25f*(x_lds[c][4*jj] + x_lds[c][4*jj+1] +
                       x_lds[c][4*jj+2] + x_lds[c][4*jj+3]);
        } else if (jj < 192) {
            int q = jj - 64;
            v = 0.5f*(x_lds[c][2*q] + x_lds[c][2*q+1]);
        } else {
            v = x_lds[c][jj - 192];
        }
        cmb[64 + e] = v;
    }
}

// ---------------------------------------------------------------------------
// Kernel 2/4: partial GEMM, M=64 fixed, k4-vectorized ACCROW inner loop.
// Block = [KCH k-chunk] x [64 j-tile]; parts[ks][64][NCOLS].
// grid = (K/KCH, NCOLS/64), block 256. KCH=64 -> 33 KB LDS, 4 blocks/CU.
// ---------------------------------------------------------------------------
template<int NCOLS, int ASTRIDE, int KCH>
__global__ __launch_bounds__(256) void mlp_part(
    const float* __restrict__ A, const float* __restrict__ W,
    float* __restrict__ parts)
{
    constexpr int APAD = KCH + 4;
    __shared__ float At[64][APAD];     // A chunk, [b][k], padded
    __shared__ float Wl[KCH][64];      // W tile [k][j]
    const int ks = blockIdx.x, k0 = ks*KCH;
    const int j0 = blockIdx.y*64;
    const int t  = threadIdx.x;

    {
        constexpr int AF4 = 64*KCH/4;
        constexpr int RF4 = KCH/4;
        #pragma unroll
        for (int f = t; f < AF4; f += 256) {
            const int row = f / RF4, c4 = f % RF4;
            *(float4*)&At[row][c4*4] =
                *(const float4*)(A + (size_t)row*ASTRIDE + k0 + c4*4);
        }
        constexpr int WF4 = KCH*16;
        #pragma unroll
        for (int f = t; f < WF4; f += 256) {
            const int row = f >> 4, c4 = f & 15;
            *(float4*)&Wl[row][c4*4] =
                *(const float4*)(W + (size_t)(k0 + row)*NCOLS + j0 + c4*4);
        }
    }
    __syncthreads();

    const int ji = t & 15, br = (t >> 4)*4;
    float4 acc0={0,0,0,0}, acc1={0,0,0,0}, acc2={0,0,0,0}, acc3={0,0,0,0};
    #pragma unroll 4
    for (int k4 = 0; k4 < KCH; k4 += 4) {
        float4 w0 = *(float4*)&Wl[k4+0][ji*4];
        float4 w1 = *(float4*)&Wl[k4+1][ji*4];
        float4 w2 = *(float4*)&Wl[k4+2][ji*4];
        float4 w3 = *(float4*)&Wl[k4+3][ji*4];
        float4 a0 = *(float4*)&At[br+0][k4];
        float4 a1 = *(float4*)&At[br+1][k4];
        float4 a2 = *(float4*)&At[br+2][k4];
        float4 a3 = *(float4*)&At[br+3][k4];
        ACCROW(acc0, a0) ACCROW(acc1, a1) ACCROW(acc2, a2) ACCROW(acc3, a3)
    }
    float* pbase = parts + (size_t)(ks*64 + br)*NCOLS + j0 + ji*4;
    *(float4*)(pbase)           = acc0;
    *(float4*)(pbase + NCOLS)   = acc1;
    *(float4*)(pbase + 2*NCOLS) = acc2;
    *(float4*)(pbase + 3*NCOLS) = acc3;
}

// ---------------------------------------------------------------------------
// Kernel 3/5: sum partials + bias, then LayerNorm + ReLU.  grid=64 (per b).
// ---------------------------------------------------------------------------
template<int N>
__global__ __launch_bounds__(256) void reduce_ln_relu(
    const float* __restrict__ parts, const float* __restrict__ bias,
    const float* __restrict__ g, const float* __restrict__ be,
    float* __restrict__ out, int KS)
{
    constexpr int NV = N/1024;      // float4 per thread
    const int b = blockIdx.x, t = threadIdx.x;
    float4 acc[NV];
    #pragma unroll
    for (int v = 0; v < NV; ++v)
        acc[v] = *(const float4*)(bias + v*1024 + t*4);
    for (int ks = 0; ks < KS; ++ks) {
        const float* p = parts + (size_t)(ks*64 + b)*N;
        #pragma unroll
        for (int v = 0; v < NV; ++v) {
            float4 q = *(const float4*)(p + v*1024 + t*4);
            acc[v].x += q.x; acc[v].y += q.y; acc[v].z += q.z; acc[v].w += q.w;
        }
    }
    float s = 0.f, s2 = 0.f;
    #pragma unroll
    for (int v = 0; v < NV; ++v) {
        s  += acc[v].x + acc[v].y + acc[v].z + acc[v].w;
        s2 += acc[v].x*acc[v].x + acc[v].y*acc[v].y +
              acc[v].z*acc[v].z + acc[v].w*acc[v].w;
    }
    #pragma unroll
    for (int off = 32; off > 0; off >>= 1) {
        s  += __shfl_down(s,  off);
        s2 += __shfl_down(s2, off);
    }
    __shared__ float red[2][4];
    const int w = t >> 6;
    if ((t & 63) == 0) { red[0][w] = s; red[1][w] = s2; }
    __syncthreads();
    float ts  = red[0][0] + red[0][1] + red[0][2] + red[0][3];
    float ts2 = red[1][0] + red[1][1] + red[1][2] + red[1][3];
    const float inv_n = 1.0f/(float)N;
    float mu  = ts*inv_n;
    float var = ts2*inv_n - mu*mu;
    float rs  = rsqrtf(var + 1e-5f);
    #pragma unroll
    for (int v = 0; v < NV; ++v) {
        const int j = v*1024 + t*4;
        float4 gv  = *(const float4*)(g + j);
        float4 bev = *(const float4*)(be + j);
        float4 o;
        o.x = fmaxf((acc[v].x - mu)*rs*gv.x + bev.x, 0.f);
        o.y = fmaxf((acc[v].y - mu)*rs*gv.y + bev.y, 0.f);
        o.z = fmaxf((acc[v].z - mu)*rs*gv.z + bev.z, 0.f);
        o.w = fmaxf((acc[v].w - mu)*rs*gv.w + bev.w, 0.f);
        *(float4*)(out + (size_t)b*N + j) = o;
    }
}

// ---------------------------------------------------------------------------
// Kernel 6: out[b,s,:] = h2[b, s*8 .. s*8+7] @ W3 + b3 -> [64,512,4096] f32
// grid = (512 row-groups of 64 rows, 4 j-slices of 1024), block 256.
// h2 reads wave-uniform -> s_load (K$); W3 in registers; NT float4 stores.
// ---------------------------------------------------------------------------
#define ROWS_D 64
__global__ __launch_bounds__(256) void final_mm(
    const float* __restrict__ h2, const float* __restrict__ W3,
    const float* __restrict__ b3, float* __restrict__ out)
{
    const int rg = blockIdx.x;
    const int js = blockIdx.y;
    const int t  = threadIdx.x;
    const int bs0 = rg*ROWS_D;
    const int j = js*1024 + t*4;
    float4 w[8];
    #pragma unroll
    for (int k = 0; k < 8; ++k) w[k] = *(const float4*)(W3 + k*4096 + j);
    const float4 bv = *(const float4*)(b3 + j);
    const float* __restrict__ hrow = h2 + (size_t)bs0*8;
    float* __restrict__ obase = out + (size_t)bs0*4096 + j;
    #pragma unroll 4
    for (int r = 0; r < ROWS_D; ++r) {
        float4 acc = bv;
        #pragma unroll
        for (int k = 0; k < 8; ++k) {
            const float hv = hrow[r*8 + k];   // wave-uniform -> s_load (K$)
            acc.x += hv*w[k].x; acc.y += hv*w[k].y;
            acc.z += hv*w[k].z; acc.w += hv*w[k].w;
        }
        nt_store4(acc, obase + (size_t)r*4096);
    }
}

// ---------------------------------------------------------------------------
extern "C" void kernel_launch(void* const* d_in, const int* in_sizes, int n_in,
                              void* d_out, int out_size, void* d_ws, size_t ws_size,
                              hipStream_t stream) {
    const float* x      = (const float*)d_in[0];
    const float* enc_W  = (const float*)d_in[1];
    const float* enc_b  = (const float*)d_in[2];
    const float* ln_s   = (const float*)d_in[3];
    const float* ln_b   = (const float*)d_in[4];
    const float* log_dt = (const float*)d_in[5];
    const float* A_re   = (const float*)d_in[6];
    const float* A_im   = (const float*)d_in[7];
    const float* C_re   = (const float*)d_in[8];
    const float* C_im   = (const float*)d_in[9];
    const float* Dp     = (const float*)d_in[10];
    const float* out_W  = (const float*)d_in[11];
    const float* out_b  = (const float*)d_in[12];
    const float* dec_W  = (const float*)d_in[13];
    const float* dec_b  = (const float*)d_in[14];
    const float* W1     = (const float*)d_in[15];
    const float* b1     = (const float*)d_in[16];
    const float* g1     = (const float*)d_in[17];
    const float* be1    = (const float*)d_in[18];
    const float* W2     = (const float*)d_in[19];
    const float* b2     = (const float*)d_in[20];
    const float* g2     = (const float*)d_in[21];
    const float* be2    = (const float*)d_in[22];
    const float* W3     = (const float*)d_in[23];
    const float* b3     = (const float*)d_in[24];
    float* out = (float*)d_out;

    float* ws = (float*)d_ws;
    float* combined = ws;                        // 64*1856
    float* parts1   = combined + 64*1856;        // 29*64*1024
    float* h1       = parts1 + 29*64*1024;       // 64*1024
    float* parts2   = h1 + 64*1024;              // 16*64*4096
    float* h2       = parts2 + 16*64*4096;       // 64*4096

    s4front<<<64, 1024, 0, stream>>>(x, enc_W, enc_b, ln_s, ln_b, log_dt,
                                     A_re, A_im, C_re, C_im, Dp,
                                     out_W, out_b, dec_W, dec_b, combined);
    mlp_part<1024,1856,64><<<dim3(29,16), 256, 0, stream>>>(combined, W1, parts1);
    reduce_ln_relu<1024><<<64, 256, 0, stream>>>(parts1, b1, g1, be1, h1, 29);
    mlp_part<4096,1024,64><<<dim3(16,64), 256, 0, stream>>>(h1, W2, parts2);
    reduce_ln_relu<4096><<<64, 256, 0, stream>>>(parts2, b2, g2, be2, h2, 16);
    final_mm<<<dim3(512,4), 256, 0, stream>>>(h2, W3, b3, out);
}

// Round 18
// 165.653 us; speedup vs baseline: 1.4343x; 1.0395x over previous
//
#include <hip/hip_runtime.h>
#include <hip/hip_bf16.h>
#include <math.h>

// Problem constants
#define BDEF 64
#define LSEQ 256
#define HD   4
#define NST  4
#define NBLK 2
#define SPLIT 4   // conv m-split factor in s4front

typedef float nfloat4 __attribute__((ext_vector_type(4)));  // native vec for nt ops

__device__ inline void nt_store4(const float4 v, float* p) {
    nfloat4 nv = {v.x, v.y, v.z, v.w};
    __builtin_nontemporal_store(nv, (nfloat4*)p);
}

// acc_row += a.{x,y,z,w} * w{0,1,2,3} (component-wise over 4 j)
#define ACCROW(accv, av)                                        \
    accv.x += av.x*w0.x + av.y*w1.x + av.z*w2.x + av.w*w3.x;    \
    accv.y += av.x*w0.y + av.y*w1.y + av.z*w2.y + av.w*w3.y;    \
    accv.z += av.x*w0.z + av.y*w1.z + av.z*w2.z + av.w*w3.z;    \
    accv.w += av.x*w0.w + av.y*w1.w + av.z*w2.w + av.w*w3.w;

// ---------------------------------------------------------------------------
// Kernel 1: K-comp + encoder + 2x S4D block + decoder + pooling
//           -> combined [64,1856].
// grid=64 (one block per batch), block=1024 (4 m-split parts x 256 l).
// ---------------------------------------------------------------------------
__global__ __launch_bounds__(1024) void s4front(
    const float* __restrict__ x, const float* __restrict__ enc_W,
    const float* __restrict__ enc_b, const float* __restrict__ ln_s,
    const float* __restrict__ ln_b, const float* __restrict__ log_dt,
    const float* __restrict__ A_re, const float* __restrict__ A_im,
    const float* __restrict__ C_re, const float* __restrict__ C_im,
    const float* __restrict__ Dp, const float* __restrict__ out_W,
    const float* __restrict__ out_b, const float* __restrict__ dec_W,
    const float* __restrict__ dec_b, float* __restrict__ combined)
{
    const int b    = blockIdx.x;
    const int t    = threadIdx.x;
    const int l    = t & 255;
    const int part = t >> 8;            // 0..3, wave-uniform
    __shared__ float Kl[NBLK][LSEQ][4];     // conv kernels, 8 KB
    __shared__ float x_lds[4][256];         // raw input row, 4 KB
    __shared__ float z_lds[256][4];         // pre-conv activations, 4 KB
    __shared__ float s4_lds[256][4];        // decoder output, 4 KB
    __shared__ float yp[SPLIT][256][4];     // conv partials, 16 KB

    // ---- SSM kernels K[i][m][h]: threads t<512, i=part, m=l ----
    if (t < 512) {
        const int i = part;             // 0 or 1
        const float tt = (float)l;
        #pragma unroll
        for (int h = 0; h < HD; ++h) {
            float dt = expf(log_dt[i*HD + h]);
            float acc = 0.f;
            #pragma unroll
            for (int n = 0; n < NST; ++n) {
                const int idx = (i*HD + h)*NST + n;
                float ar = -expf(A_re[idx]);     // Re(A)
                float ai = A_im[idx];            // Im(A)
                float dr = ar*dt, di = ai*dt;    // dtA
                float er  = expf(dr);            // Bd = (exp(dtA)-1)/A
                float e1r = er*cosf(di) - 1.0f;
                float e1i = er*sinf(di);
                float inv = 1.0f/(ar*ar + ai*ai);
                float bdr = (e1r*ar + e1i*ai)*inv;
                float bdi = (e1i*ar - e1r*ai)*inv;
                float cr = C_re[idx], ci = C_im[idx];
                float cbr = cr*bdr - ci*bdi;     // C*Bd
                float cbi = cr*bdi + ci*bdr;
                float em = expf(dr*tt);          // vand = exp(dtA*t)
                float vr = em*cosf(di*tt);
                float vi = em*sinf(di*tt);
                acc += cbr*vr - cbi*vi;
            }
            Kl[i][l][h] = 2.0f*acc;
        }
    }

    if (part == 0) {
        #pragma unroll
        for (int c = 0; c < 4; ++c)
            x_lds[c][l] = x[(b*4 + c)*256 + l];
    }
    __syncthreads();

    // encoder (all parts duplicate; register-only state)
    float u[4];
    #pragma unroll
    for (int h = 0; h < 4; ++h) {
        float a = enc_b[h];
        #pragma unroll
        for (int c = 0; c < 4; ++c) a += x_lds[c][l]*enc_W[c*4 + h];
        u[h] = a;
    }

    const int mlim = l | 63;            // wave-uniform conv bound
    const int m0   = part*64;           // wave-uniform part range start

    for (int i = 0; i < NBLK; ++i) {
        // prenorm LN over H=4 (all parts duplicate)
        float mu = 0.25f*(u[0]+u[1]+u[2]+u[3]);
        float var = 0.f;
        #pragma unroll
        for (int h = 0; h < 4; ++h) { float d = u[h]-mu; var += d*d; }
        var *= 0.25f;
        float rs = rsqrtf(var + 1e-5f);
        float z[4];
        #pragma unroll
        for (int h = 0; h < 4; ++h)
            z[h] = (u[h]-mu)*rs*ln_s[i*4 + h] + ln_b[i*4 + h];
        if (part == 0)
            *(float4*)&z_lds[l][0] = make_float4(z[0], z[1], z[2], z[3]);
        __syncthreads();   // A: z_lds visible to all parts

        // conv partial: m in [m0, min(m0+63, mlim)], mask m<=l
        float y0 = 0.f, y1 = 0.f, y2 = 0.f, y3 = 0.f;
        const int mhi = min(m0 + 63, mlim);
        #pragma unroll 4
        for (int m = m0; m <= mhi; ++m) {
            float4 kk = *(const float4*)&Kl[i][m][0];
            int p = (l - m) & 255;
            float4 zz = *(const float4*)&z_lds[p][0];
            if (m <= l) {
                y0 += kk.x*zz.x; y1 += kk.y*zz.y;
                y2 += kk.z*zz.z; y3 += kk.w*zz.w;
            }
        }
        *(float4*)&yp[part][l][0] = make_float4(y0, y1, y2, y3);
        __syncthreads();   // B: partials ready

        float4 p0 = *(const float4*)&yp[0][l][0];
        float4 p1 = *(const float4*)&yp[1][l][0];
        float4 p2 = *(const float4*)&yp[2][l][0];
        float4 p3 = *(const float4*)&yp[3][l][0];
        float y[4] = { p0.x+p1.x+p2.x+p3.x, p0.y+p1.y+p2.y+p3.y,
                       p0.z+p1.z+p2.z+p3.z, p0.w+p1.w+p2.w+p3.w };
        // skip + gelu (tanh approximation) — all parts duplicate
        #pragma unroll
        for (int h = 0; h < 4; ++h) {
            float v = y[h] + Dp[i*4 + h]*z[h];
            float inner = 0.7978845608028654f*(v + 0.044715f*v*v*v);
            y[h] = 0.5f*v*(1.0f + tanhf(inner));
        }
        // output projection + residual
        #pragma unroll
        for (int k = 0; k < 4; ++k) {
            float a = out_b[i*4 + k];
            #pragma unroll
            for (int h = 0; h < 4; ++h) a += y[h]*out_W[(i*4 + h)*4 + k];
            u[k] += a;
        }
        __syncthreads();   // C: yp/z_lds reads done before next-iter rewrite
    }

    // decoder (part 0 writes; all parts hold identical u)
    if (part == 0) {
        #pragma unroll
        for (int h = 0; h < 4; ++h) {
            float a = dec_b[h];
            #pragma unroll
            for (int k = 0; k < 4; ++k) a += u[k]*dec_W[k*4 + h];
            s4_lds[l][h] = a;
        }
    }
    __syncthreads();

    float* cmb = combined + b*1856;
    // z16: [4,16] pooled (window 16), flattened h*16+k
    if (t < 64) {
        int h = t >> 4, kk = t & 15;
        float a = 0.f;
        #pragma unroll
        for (int j = 0; j < 16; ++j) a += s4_lds[kk*16 + j][h];
        cmb[t] = a*(1.0f/16.0f);
    }
    // fpp: [4,448] = concat(pool64(win4), pool128(win2), raw256), offset 64
    for (int e = t; e < 1792; e += 1024) {
        int c = e/448, jj = e%448;
        float v;
        if (jj < 64) {
            v = 0.25f*(x_lds[c][4*jj] + x_lds[c][4*jj+1] +
                       x_lds[c][4*jj+2] + x_lds[c][4*jj+3]);
        } else if (jj < 192) {
            int q = jj - 64;
            v = 0.5f*(x_lds[c][2*q] + x_lds[c][2*q+1]);
        } else {
            v = x_lds[c][jj - 192];
        }
        cmb[64 + e] = v;
    }
}

// ---------------------------------------------------------------------------
// Kernel 2/4: partial GEMM, M=64 fixed, k4-vectorized ACCROW inner loop.
// Block = [KCH k-chunk] x [64 j-tile]; parts[ks][64][NCOLS].
// grid = (K/KCH, NCOLS/64), block 256. KCH=64 -> 33 KB LDS, 4 blocks/CU.
// ---------------------------------------------------------------------------
template<int NCOLS, int ASTRIDE, int KCH>
__global__ __launch_bounds__(256) void mlp_part(
    const float* __restrict__ A, const float* __restrict__ W,
    float* __restrict__ parts)
{
    constexpr int APAD = KCH + 4;
    __shared__ float At[64][APAD];     // A chunk, [b][k], padded
    __shared__ float Wl[KCH][64];      // W tile [k][j]
    const int ks = blockIdx.x, k0 = ks*KCH;
    const int j0 = blockIdx.y*64;
    const int t  = threadIdx.x;

    {
        constexpr int AF4 = 64*KCH/4;
        constexpr int RF4 = KCH/4;
        #pragma unroll
        for (int f = t; f < AF4; f += 256) {
            const int row = f / RF4, c4 = f % RF4;
            *(float4*)&At[row][c4*4] =
                *(const float4*)(A + (size_t)row*ASTRIDE + k0 + c4*4);
        }
        constexpr int WF4 = KCH*16;
        #pragma unroll
        for (int f = t; f < WF4; f += 256) {
            const int row = f >> 4, c4 = f & 15;
            *(float4*)&Wl[row][c4*4] =
                *(const float4*)(W + (size_t)(k0 + row)*NCOLS + j0 + c4*4);
        }
    }
    __syncthreads();

    const int ji = t & 15, br = (t >> 4)*4;
    float4 acc0={0,0,0,0}, acc1={0,0,0,0}, acc2={0,0,0,0}, acc3={0,0,0,0};
    #pragma unroll 4
    for (int k4 = 0; k4 < KCH; k4 += 4) {
        float4 w0 = *(float4*)&Wl[k4+0][ji*4];
        float4 w1 = *(float4*)&Wl[k4+1][ji*4];
        float4 w2 = *(float4*)&Wl[k4+2][ji*4];
        float4 w3 = *(float4*)&Wl[k4+3][ji*4];
        float4 a0 = *(float4*)&At[br+0][k4];
        float4 a1 = *(float4*)&At[br+1][k4];
        float4 a2 = *(float4*)&At[br+2][k4];
        float4 a3 = *(float4*)&At[br+3][k4];
        ACCROW(acc0, a0) ACCROW(acc1, a1) ACCROW(acc2, a2) ACCROW(acc3, a3)
    }
    float* pbase = parts + (size_t)(ks*64 + br)*NCOLS + j0 + ji*4;
    *(float4*)(pbase)           = acc0;
    *(float4*)(pbase + NCOLS)   = acc1;
    *(float4*)(pbase + 2*NCOLS) = acc2;
    *(float4*)(pbase + 3*NCOLS) = acc3;
}

// ---------------------------------------------------------------------------
// Kernel 3/5: sum partials + bias, then LayerNorm + ReLU.  grid=64 (per b).
// ---------------------------------------------------------------------------
template<int N>
__global__ __launch_bounds__(256) void reduce_ln_relu(
    const float* __restrict__ parts, const float* __restrict__ bias,
    const float* __restrict__ g, const float* __restrict__ be,
    float* __restrict__ out, int KS)
{
    constexpr int NV = N/1024;      // float4 per thread
    const int b = blockIdx.x, t = threadIdx.x;
    float4 acc[NV];
    #pragma unroll
    for (int v = 0; v < NV; ++v)
        acc[v] = *(const float4*)(bias + v*1024 + t*4);
    for (int ks = 0; ks < KS; ++ks) {
        const float* p = parts + (size_t)(ks*64 + b)*N;
        #pragma unroll
        for (int v = 0; v < NV; ++v) {
            float4 q = *(const float4*)(p + v*1024 + t*4);
            acc[v].x += q.x; acc[v].y += q.y; acc[v].z += q.z; acc[v].w += q.w;
        }
    }
    float s = 0.f, s2 = 0.f;
    #pragma unroll
    for (int v = 0; v < NV; ++v) {
        s  += acc[v].x + acc[v].y + acc[v].z + acc[v].w;
        s2 += acc[v].x*acc[v].x + acc[v].y*acc[v].y +
              acc[v].z*acc[v].z + acc[v].w*acc[v].w;
    }
    #pragma unroll
    for (int off = 32; off > 0; off >>= 1) {
        s  += __shfl_down(s,  off);
        s2 += __shfl_down(s2, off);
    }
    __shared__ float red[2][4];
    const int w = t >> 6;
    if ((t & 63) == 0) { red[0][w] = s; red[1][w] = s2; }
    __syncthreads();
    float ts  = red[0][0] + red[0][1] + red[0][2] + red[0][3];
    float ts2 = red[1][0] + red[1][1] + red[1][2] + red[1][3];
    const float inv_n = 1.0f/(float)N;
    float mu  = ts*inv_n;
    float var = ts2*inv_n - mu*mu;
    float rs  = rsqrtf(var + 1e-5f);
    #pragma unroll
    for (int v = 0; v < NV; ++v) {
        const int j = v*1024 + t*4;
        float4 gv  = *(const float4*)(g + j);
        float4 bev = *(const float4*)(be + j);
        float4 o;
        o.x = fmaxf((acc[v].x - mu)*rs*gv.x + bev.x, 0.f);
        o.y = fmaxf((acc[v].y - mu)*rs*gv.y + bev.y, 0.f);
        o.z = fmaxf((acc[v].z - mu)*rs*gv.z + bev.z, 0.f);
        o.w = fmaxf((acc[v].w - mu)*rs*gv.w + bev.w, 0.f);
        *(float4*)(out + (size_t)b*N + j) = o;
    }
}

// ---------------------------------------------------------------------------
// Kernel 6: out[b,s,:] = h2[b, s*8 .. s*8+7] @ W3 + b3 -> [64,512,4096] f32
// grid = (512 row-groups of 64 rows, 4 j-slices of 1024), block 256.
// h2 reads wave-uniform -> s_load (K$); W3 in registers; NT float4 stores.
// ---------------------------------------------------------------------------
#define ROWS_D 64
__global__ __launch_bounds__(256) void final_mm(
    const float* __restrict__ h2, const float* __restrict__ W3,
    const float* __restrict__ b3, float* __restrict__ out)
{
    const int rg = blockIdx.x;
    const int js = blockIdx.y;
    const int t  = threadIdx.x;
    const int bs0 = rg*ROWS_D;
    const int j = js*1024 + t*4;
    float4 w[8];
    #pragma unroll
    for (int k = 0; k < 8; ++k) w[k] = *(const float4*)(W3 + k*4096 + j);
    const float4 bv = *(const float4*)(b3 + j);
    const float* __restrict__ hrow = h2 + (size_t)bs0*8;
    float* __restrict__ obase = out + (size_t)bs0*4096 + j;
    #pragma unroll 4
    for (int r = 0; r < ROWS_D; ++r) {
        float4 acc = bv;
        #pragma unroll
        for (int k = 0; k < 8; ++k) {
            const float hv = hrow[r*8 + k];   // wave-uniform -> s_load (K$)
            acc.x += hv*w[k].x; acc.y += hv*w[k].y;
            acc.z += hv*w[k].z; acc.w += hv*w[k].w;
        }
        nt_store4(acc, obase + (size_t)r*4096);
    }
}

// ---------------------------------------------------------------------------
extern "C" void kernel_launch(void* const* d_in, const int* in_sizes, int n_in,
                              void* d_out, int out_size, void* d_ws, size_t ws_size,
                              hipStream_t stream) {
    const float* x      = (const float*)d_in[0];
    const float* enc_W  = (const float*)d_in[1];
    const float* enc_b  = (const float*)d_in[2];
    const float* ln_s   = (const float*)d_in[3];
    const float* ln_b   = (const float*)d_in[4];
    const float* log_dt = (const float*)d_in[5];
    const float* A_re   = (const float*)d_in[6];
    const float* A_im   = (const float*)d_in[7];
    const float* C_re   = (const float*)d_in[8];
    const float* C_im   = (const float*)d_in[9];
    const float* Dp     = (const float*)d_in[10];
    const float* out_W  = (const float*)d_in[11];
    const float* out_b  = (const float*)d_in[12];
    const float* dec_W  = (const float*)d_in[13];
    const float* dec_b  = (const float*)d_in[14];
    const float* W1     = (const float*)d_in[15];
    const float* b1     = (const float*)d_in[16];
    const float* g1     = (const float*)d_in[17];
    const float* be1    = (const float*)d_in[18];
    const float* W2     = (const float*)d_in[19];
    const float* b2     = (const float*)d_in[20];
    const float* g2     = (const float*)d_in[21];
    const float* be2    = (const float*)d_in[22];
    const float* W3     = (const float*)d_in[23];
    const float* b3     = (const float*)d_in[24];
    float* out = (float*)d_out;

    float* ws = (float*)d_ws;
    float* combined = ws;                        // 64*1856
    float* parts1   = combined + 64*1856;        // 29*64*1024
    float* h1       = parts1 + 29*64*1024;       // 64*1024
    float* parts2   = h1 + 64*1024;              // 16*64*4096
    float* h2       = parts2 + 16*64*4096;       // 64*4096

    s4front<<<64, 1024, 0, stream>>>(x, enc_W, enc_b, ln_s, ln_b, log_dt,
                                     A_re, A_im, C_re, C_im, Dp,
                                     out_W, out_b, dec_W, dec_b, combined);
    mlp_part<1024,1856,64><<<dim3(29,16), 256, 0, stream>>>(combined, W1, parts1);
    reduce_ln_relu<1024><<<64, 256, 0, stream>>>(parts1, b1, g1, be1, h1, 29);
    mlp_part<4096,1024,64><<<dim3(16,64), 256, 0, stream>>>(h1, W2, parts2);
    reduce_ln_relu<4096><<<64, 256, 0, stream>>>(parts2, b2, g2, be2, h2, 16);
    final_mm<<<dim3(512,4), 256, 0, stream>>>(h2, W3, b3, out);
}